// Round 17
// baseline (73.033 us; speedup 1.0000x reference)
//
#include <hip/hip_runtime.h>
#include <cstdint>
#include <cstddef>

#define NB 512
#define NL 32
#define KD 512     // P*D
#define KSLAB 128  // k-range per cost block
#define PASS 64    // k per staging pass (2 passes/block)

// swizzled float-offset of chunk ch (4 floats) of row `row` in a [32][64] pass buffer.
__device__ __forceinline__ int swz64(int row, int ch) {
  int csw = (ch ^ (row >> 1)) & 15;
  return row * PASS + csw * 4;
}

// ---------------- cost kernel: 2048 blocks x 128 thr, one tranche ----------------
// R14 null explained: 256-thr blocks cap at 4 blocks/CU (VGPR 116 -> 4 waves/SIMD)
// -> 2048 blocks = 2 tranches, wall stuck at ~22us. 128-thr blocks (2 waves,
// 16 KB LDS) give 8 blocks/CU = ONE tranche at the same 16 waves/CU.
__global__ __launch_bounds__(128, 2)
void cost_kernel(const float* __restrict__ pred, const float* __restrict__ tgt,
                 float* __restrict__ cost_part) {
  __shared__ float smem[4096];   // 16 KB: predH[0..2048), tgtH[2048..4096); partials alias
  const int bid = blockIdx.x;
  const int b  = bid >> 2;
  const int ks = (bid & 3) * KSLAB;
  const int tid = threadIdx.x;
  float* predH = smem;
  float* tgtH  = smem + 2048;

  const int w = tid >> 6, l = tid & 63;   // 2 waves; wave w owns a 32-float k-slice/pass
  const int ti = l >> 3, tj = l & 7;      // 8x8 lanes of 4x4 output tiles
  float acc[4][4];
#pragma unroll
  for (int a = 0; a < 4; ++a)
#pragma unroll
    for (int c2 = 0; c2 < 4; ++c2) acc[a][c2] = 0.f;

  for (int hp = 0; hp < 2; ++hp) {        // 2 passes cover the block's k=128
    __syncthreads();
    const size_t base = (size_t)b * (NL * KD) + ks + hp * PASS;
#pragma unroll
    for (int it = 0; it < 4; ++it) {
      int chunk = tid + it * 128;          // 0..511 -> row, chunk-in-row (16/row)
      int row = chunk >> 4, ch = chunk & 15;
      const float4 pv = *reinterpret_cast<const float4*>(pred + base + (size_t)row * KD + ch * 4);
      const float4 tv = *reinterpret_cast<const float4*>(tgt  + base + (size_t)row * KD + ch * 4);
      int off = swz64(row, ch);
      *reinterpret_cast<float4*>(predH + off) = pv;
      *reinterpret_cast<float4*>(tgtH  + off) = tv;
    }
    __syncthreads();
#pragma unroll
    for (int c0 = 0; c0 < 8; ++c0) {
      const int c = (w << 3) + c0;         // wave's 8 chunks of this pass
      float4 pr[4], tg[4];
#pragma unroll
      for (int r = 0; r < 4; ++r) {
        pr[r] = *reinterpret_cast<const float4*>(predH + swz64(4 * ti + r, c));
        tg[r] = *reinterpret_cast<const float4*>(tgtH  + swz64(4 * tj + r, c));
      }
#pragma unroll
      for (int a = 0; a < 4; ++a)
#pragma unroll
        for (int c2 = 0; c2 < 4; ++c2) {
          float d;
          d = pr[a].x - tg[c2].x; acc[a][c2] += d * d;
          d = pr[a].y - tg[c2].y; acc[a][c2] += d * d;
          d = pr[a].z - tg[c2].z; acc[a][c2] += d * d;
          d = pr[a].w - tg[c2].w; acc[a][c2] += d * d;
        }
    }
  }
  __syncthreads();   // staging reads done; alias LDS with 2x1024 partials
  // disjoint bit-fields: addr = (ti&3) | 4*(j>>2) | 32*(i&3) | 128*(j&3) | 512*(ti>>2)
#pragma unroll
  for (int a = 0; a < 4; ++a)
#pragma unroll
    for (int c2 = 0; c2 < 4; ++c2)
      smem[w * 1024 + (ti & 3) + 4 * tj + 32 * a + 128 * c2 + 512 * (ti >> 2)] = acc[a][c2];
  __syncthreads();
  // thread t reduces outputs i = t>>2, j = (t&3)*8 .. +7  (2 float4 stores)
  const int i = tid >> 2, j0 = (tid & 3) * 8;
  const int ti3 = i >> 2;
  float ov[8];
#pragma unroll
  for (int kk = 0; kk < 8; ++kk) {
    int j = j0 + kk;
    int ad = (ti3 & 3) + 4 * (j >> 2) + 32 * (i & 3) + 128 * (j & 3) + 512 * (ti3 >> 2);
    ov[kk] = smem[ad] + smem[ad + 1024];
  }
  float* dst = cost_part + (size_t)bid * 1024 + i * 32 + j0;
  *reinterpret_cast<float4*>(dst)     = make_float4(ov[0], ov[1], ov[2], ov[3]);
  *reinterpret_cast<float4*>(dst + 4) = make_float4(ov[4], ov[5], ov[6], ov[7]);
}

// ---------------- hungarian + fused finalize: 512 blocks x 64 thr ----------------
__device__ __forceinline__ float readlane_f(float x, int lane) {
  return __int_as_float(__builtin_amdgcn_readlane(__float_as_int(x), lane));
}
__device__ __forceinline__ int readlane_i(int x, int lane) {
  return __builtin_amdgcn_readlane(x, lane);
}

template<int CTRL, int RM>
__device__ __forceinline__ unsigned int dppumin(unsigned int x) {
  unsigned int m = (unsigned int)__builtin_amdgcn_update_dpp((int)x, (int)x, CTRL, RM, 0xf, false);
  return x < m ? x : m;   // v_min_u32
}
// u32 min over lanes 0..31, returned as wave-uniform scalar
__device__ __forceinline__ unsigned int wave_umin32_bcast(unsigned int x) {
  x = dppumin<0xB1, 0xf>(x);   // quad_perm xor1
  x = dppumin<0x4E, 0xf>(x);   // quad_perm xor2
  x = dppumin<0x124, 0xf>(x);  // row_ror:4
  x = dppumin<0x128, 0xf>(x);  // row_ror:8 -> row16 min everywhere
  x = dppumin<0x142, 0xa>(x);  // row_bcast:15 -> lanes 16..31 = min(lanes 0..31)
  return (unsigned int)__builtin_amdgcn_readlane((int)x, 31);
}

__global__ __launch_bounds__(64)
void hung_kernel(const float* __restrict__ cost_part,
                 const float* __restrict__ prob,
                 const float* __restrict__ lmask,
                 const int* __restrict__ clf,
                 float* __restrict__ part,
                 unsigned int* __restrict__ counter,   // zeroed per call
                 float* __restrict__ out) {
  __shared__ float cs[1024];    // cost[32][32]: row-select = 1 conflict-free ds_read_b32
  const int b = blockIdx.x;
  const int lane = threadIdx.x;

  // stage cost = sum of the batch's four K-slab partial planes
  {
    const float4* p0 = reinterpret_cast<const float4*>(cost_part + (size_t)(4 * b + 0) * 1024);
    const float4* p1 = reinterpret_cast<const float4*>(cost_part + (size_t)(4 * b + 1) * 1024);
    const float4* p2 = reinterpret_cast<const float4*>(cost_part + (size_t)(4 * b + 2) * 1024);
    const float4* p3 = reinterpret_cast<const float4*>(cost_part + (size_t)(4 * b + 3) * 1024);
    float4* cs4 = reinterpret_cast<float4*>(cs);
#pragma unroll
    for (int k = 0; k < 4; ++k) {
      int i = lane + 64 * k;
      float4 x0 = p0[i], x1 = p1[i], x2 = p2[i], x3 = p3[i];
      cs4[i] = make_float4((x0.x + x1.x) + (x2.x + x3.x),
                           (x0.y + x1.y) + (x2.y + x3.y),
                           (x0.z + x1.z) + (x2.z + x3.z),
                           (x0.w + x1.w) + (x2.w + x3.w));
    }
  }

  float lm = (lane < 32) ? lmask[b * 32 + lane] : 0.f;
  const int n = __popcll(__ballot(lm > 0.5f));
  float clfpart = 0.f;
  if (lane < 32 && lm > 0.5f) {
    int cc = clf[b * 32 + lane];
    clfpart = -logf(prob[(size_t)(b * 32 + lane) * 2 + cc]);
  }
  __syncthreads();   // cs visible

  const float FINF = 1e30f;
  const bool activecol = (lane < n);
  const int cl = lane & 31;   // lanes 32..63 mirror -> same-addr broadcast (free)

  // Reference-faithful broken JV (minv/way never persisted in the python):
  // each step: fresh argmin over free cols of cost[i0][j]-u[i0]-v[j];
  // "augment" collapses to p[j_final] = ri. Packed sortable-u32 argmin
  // (R15-proven): 5 LSBs hold lane idx -> one v_min_u32 DPP cascade gives
  // min AND first-index argmin in one scalar.
  float u_r = 0.f, v_j = 0.f;
  int p_j = -1;

  for (int ri = 0; ri < n; ++ri) {
    int i0 = ri;
    bool usedc = false;
    bool usedr = (lane == ri);
    float rowv = cs[i0 * 32 + cl];
    float u0 = readlane_f(u_r, i0);
    while (true) {
      float key = rowv - v_j;                   // reduced cost (sans uniform u0)
      bool act = activecol && !usedc;
      float m = act ? key : FINF;
      unsigned int mu = __float_as_uint(m);
      mu ^= (unsigned int)((int)mu >> 31) | 0x80000000u;   // monotone f32->u32
      unsigned int packed = (mu & 0xFFFFFFE0u) | (unsigned int)cl;
      unsigned int pmin = wave_umin32_bcast(packed);
      int j1 = (int)(pmin & 31u);               // first-min column
      float mnv = readlane_f(m, j1);            // exact min value
      int pj1 = readlane_i(p_j, j1);
      float delta = mnv - u0;
      if (usedr) u_r += delta;                  // u[p[used]] += delta
      if (usedc) v_j -= delta;                  // v[used]    -= delta
      if (pj1 < 0) {                            // free column -> p[j1] = ri, done
        if (lane == j1) p_j = ri;
        break;
      }
      usedc = usedc || (lane == j1);
      usedr = usedr || (lane == pj1);
      i0 = pj1;
      rowv = cs[i0 * 32 + cl];
      u0 = readlane_f(u_r, i0);                 // post-update u[i0]
    }
  }

  // column j matched to row p[j] -> contributes cost[p[j]][j]
  int pj = p_j < 0 ? 0 : p_j;
  float a = activecol ? cs[pj * 32 + cl] : 0.f;
#pragma unroll
  for (int off = 32; off; off >>= 1) {
    a += __shfl_xor(a, off);
    clfpart += __shfl_xor(clfpart, off);
  }
  if (lane == 0) {
    part[b * 3 + 0] = a;
    part[b * 3 + 1] = clfpart;
    part[b * 3 + 2] = (float)n;
  }

  // ---- fused finalize: last arrival reduces (R9-proven ticket pattern) ----
  __threadfence();                       // release part[b]
  unsigned int t = 0;
  if (lane == 0) t = atomicAdd(counter, 1u);
  t = (unsigned int)__shfl((int)t, 0);
  if (t == NB - 1u) {
    __threadfence();                     // acquire all blocks' part writes
    volatile const float* vp = part;
    double csum = 0.0, lsum = 0.0, nsum = 0.0;
    for (int i = lane; i < NB; i += 64) {
      csum += (double)vp[i * 3 + 0];
      lsum += (double)vp[i * 3 + 1];
      nsum += (double)vp[i * 3 + 2];
    }
#pragma unroll
    for (int off = 32; off; off >>= 1) {
      csum += __shfl_xor(csum, off);
      lsum += __shfl_xor(lsum, off);
      nsum += __shfl_xor(nsum, off);
    }
    if (lane == 0) {
      out[0] = (float)(csum / (nsum * 256.0));  // / sum(point_masks) = 256*sum(n)
      out[1] = (float)(lsum / nsum);            // / sum(line_masks)
    }
  }
}

extern "C" void kernel_launch(void* const* d_in, const int* in_sizes, int n_in,
                              void* d_out, int out_size, void* d_ws, size_t ws_size,
                              hipStream_t stream) {
  const float* pred = (const float*)d_in[0];   // [512,32,256,2] f32
  const float* prob = (const float*)d_in[1];   // [512,32,2] f32
  const float* tgt  = (const float*)d_in[2];   // [512,32,256,2] f32
  const float* lm   = (const float*)d_in[3];   // [512,32] f32
  const int*   clf  = (const int*)d_in[4];     // [512,32] i32

  float* cost_part = (float*)d_ws;                       // 2048*1024 f32 = 8 MB
  float* part = cost_part + (size_t)2048 * 1024;         // 512*3 f32
  unsigned int* counter = (unsigned int*)(part + NB * 3);

  hipMemsetAsync(counter, 0, sizeof(unsigned int), stream);  // stream-ordered, capturable
  cost_kernel<<<NB * 4, 128, 0, stream>>>(pred, tgt, cost_part);
  hung_kernel<<<NB, 64, 0, stream>>>(cost_part, prob, lm, clf, part, counter,
                                     (float*)d_out);
}

// Round 18
// 70.144 us; speedup vs baseline: 1.0412x; 1.0412x over previous
//
#include <hip/hip_runtime.h>
#include <cstdint>
#include <cstddef>

#define NB 512
#define NL 32
#define KD 512     // P*D
#define KSLAB 128  // k-range per cost block (quarter-K)
#define PASS 128   // k per staging pass

// swizzled float-offset of chunk ch (4 floats) of row `row` in a [32][128] pass buffer.
__device__ __forceinline__ int swz128(int row, int ch) {
  int csw = (ch & ~15) | ((ch ^ (row >> 1)) & 15);
  return row * PASS + csw * 4;
}

// ---------------- cost kernel: 2048 blocks x 256 thr (R15-proven; byte-identical) ----------------
__global__ __launch_bounds__(256, 2)
void cost_kernel(const float* __restrict__ pred, const float* __restrict__ tgt,
                 float* __restrict__ cost_part) {
  __shared__ float smem[8192];   // 32 KB: predH[0..4096), tgtH[4096..8192); partials alias
  const int bid = blockIdx.x;
  const int b  = bid >> 2;
  const int ks = (bid & 3) * KSLAB;
  const int tid = threadIdx.x;
  float* predH = smem;
  float* tgtH  = smem + 4096;

  const int w = tid >> 6, l = tid & 63;
  const int ti = l >> 3, tj = l & 7;
  float acc[4][4];
#pragma unroll
  for (int a = 0; a < 4; ++a)
#pragma unroll
    for (int c2 = 0; c2 < 4; ++c2) acc[a][c2] = 0.f;

  const size_t base = (size_t)b * (NL * KD) + ks;
#pragma unroll
  for (int it = 0; it < 4; ++it) {
    int chunk = tid + it * 256;
    int row = chunk >> 5, ch = chunk & 31;
    const float4 pv = *reinterpret_cast<const float4*>(pred + base + (size_t)row * KD + ch * 4);
    const float4 tv = *reinterpret_cast<const float4*>(tgt  + base + (size_t)row * KD + ch * 4);
    int off = swz128(row, ch);
    *reinterpret_cast<float4*>(predH + off) = pv;
    *reinterpret_cast<float4*>(tgtH  + off) = tv;
  }
  __syncthreads();
#pragma unroll
  for (int c0 = 0; c0 < 8; ++c0) {
    const int c = (w << 3) + c0;
    float4 pr[4], tg[4];
#pragma unroll
    for (int r = 0; r < 4; ++r) {
      pr[r] = *reinterpret_cast<const float4*>(predH + swz128(4 * ti + r, c));
      tg[r] = *reinterpret_cast<const float4*>(tgtH  + swz128(4 * tj + r, c));
    }
#pragma unroll
    for (int a = 0; a < 4; ++a)
#pragma unroll
      for (int c2 = 0; c2 < 4; ++c2) {
        float d;
        d = pr[a].x - tg[c2].x; acc[a][c2] += d * d;
        d = pr[a].y - tg[c2].y; acc[a][c2] += d * d;
        d = pr[a].z - tg[c2].z; acc[a][c2] += d * d;
        d = pr[a].w - tg[c2].w; acc[a][c2] += d * d;
      }
  }
  __syncthreads();
#pragma unroll
  for (int a = 0; a < 4; ++a)
#pragma unroll
    for (int c2 = 0; c2 < 4; ++c2)
      smem[w * 1024 + (ti & 3) + 4 * tj + 32 * a + 128 * c2 + 512 * (ti >> 2)] = acc[a][c2];
  __syncthreads();
  const int ti2 = tid >> 5, a2 = (tid >> 3) & 3, tj2 = tid & 7;
  float ov[4];
#pragma unroll
  for (int k = 0; k < 4; ++k) {
    int ad = (ti2 & 3) + 4 * tj2 + 32 * a2 + 128 * k + 512 * (ti2 >> 2);
    ov[k] = (smem[ad] + smem[ad + 1024]) + (smem[ad + 2048] + smem[ad + 3072]);
  }
  *reinterpret_cast<float4*>(cost_part + (size_t)bid * 1024 + tid * 4) =
      make_float4(ov[0], ov[1], ov[2], ov[3]);
}

// ---------------- hungarian + fused finalize: 512 blocks x 64 thr ----------------
// All-VALU loop chain: no readlane/SGPR round-trips in the walk.
template<int CTRL, int RM>
__device__ __forceinline__ unsigned int dppumin(unsigned int x) {
  unsigned int m = (unsigned int)__builtin_amdgcn_update_dpp((int)x, (int)x, CTRL, RM, 0xf, false);
  return x < m ? x : m;   // v_min_u32
}
__device__ __forceinline__ unsigned int swz_xor16(unsigned int x) {
  return (unsigned int)__builtin_amdgcn_ds_swizzle((int)x, 0x401F);  // lane ^= 16 (in 32-group)
}
__device__ __forceinline__ int bperm_i(int x, int srclane) {
  return __builtin_amdgcn_ds_bpermute(srclane << 2, x);
}
__device__ __forceinline__ float bperm_f(float x, int srclane) {
  return __int_as_float(__builtin_amdgcn_ds_bpermute(srclane << 2, __float_as_int(x)));
}
// inverse of the monotone f32->u32 sortable map
__device__ __forceinline__ float unsort_f(unsigned int y) {
  unsigned int x = (y & 0x80000000u) ? (y ^ 0x80000000u) : ~y;
  return __uint_as_float(x);
}

__global__ __launch_bounds__(64)
void hung_kernel(const float* __restrict__ cost_part,
                 const float* __restrict__ prob,
                 const float* __restrict__ lmask,
                 const int* __restrict__ clf,
                 float* __restrict__ part,
                 unsigned int* __restrict__ counter,   // zeroed per call
                 float* __restrict__ out) {
  __shared__ float cs[1024];    // cost[32][32]: row read = conflict-free ds_read_b32
  const int b = blockIdx.x;
  const int lane = threadIdx.x;
  const int cl = lane & 31;     // lanes 32..63 MIRROR lanes 0..31 (uniform control flow)

  // stage cost = sum of the batch's four K-slab partial planes
  {
    const float4* p0 = reinterpret_cast<const float4*>(cost_part + (size_t)(4 * b + 0) * 1024);
    const float4* p1 = reinterpret_cast<const float4*>(cost_part + (size_t)(4 * b + 1) * 1024);
    const float4* p2 = reinterpret_cast<const float4*>(cost_part + (size_t)(4 * b + 2) * 1024);
    const float4* p3 = reinterpret_cast<const float4*>(cost_part + (size_t)(4 * b + 3) * 1024);
    float4* cs4 = reinterpret_cast<float4*>(cs);
#pragma unroll
    for (int k = 0; k < 4; ++k) {
      int i = lane + 64 * k;
      float4 x0 = p0[i], x1 = p1[i], x2 = p2[i], x3 = p3[i];
      cs4[i] = make_float4((x0.x + x1.x) + (x2.x + x3.x),
                           (x0.y + x1.y) + (x2.y + x3.y),
                           (x0.z + x1.z) + (x2.z + x3.z),
                           (x0.w + x1.w) + (x2.w + x3.w));
    }
  }

  float lm = (lane < 32) ? lmask[b * 32 + lane] : 0.f;
  const int n = __popcll(__ballot(lm > 0.5f));
  float clfpart = 0.f;
  if (lane < 32 && lm > 0.5f) {
    int cc = clf[b * 32 + lane];
    clfpart = -logf(prob[(size_t)(b * 32 + lane) * 2 + cc]);
  }
  __syncthreads();   // cs visible

  const float FINF = 1e30f;
  const bool activecol = (cl < n);   // mirrored across halves

  // Reference-faithful broken JV (minv/way never persisted in the python).
  // Packed sortable-u32 argmin (R15-proven) + all-VALU plumbing:
  //  - final min-broadcast via ds_swizzle xor16 (no readlane)
  //  - p[j1], u[i0] via ds_bpermute (no SGPR round-trip)
  //  - exact-min readlane dropped: mnv from packed key with 5 LSBs zeroed
  //    (<=31 ulp error in delta; same order as the tie quantization already
  //     shipping in R15/R17, which measured absmax 0.0)
  float u_r = 0.f, v_j = 0.f;
  int p_j = -1;

  for (int ri = 0; ri < n; ++ri) {
    int i0 = ri;
    bool usedc = false;
    bool usedr = (cl == ri);
    float rowv = cs[i0 * 32 + cl];
    float u0 = bperm_f(u_r, i0);
    while (true) {
      float key = rowv - v_j;                   // reduced cost (sans uniform u0)
      float m = (activecol && !usedc) ? key : FINF;
      unsigned int mu = __float_as_uint(m);
      mu ^= (unsigned int)((int)mu >> 31) | 0x80000000u;   // monotone f32->u32
      unsigned int packed = (mu & 0xFFFFFFE0u) | (unsigned int)cl;
      packed = dppumin<0xB1, 0xf>(packed);      // quad_perm xor1
      packed = dppumin<0x4E, 0xf>(packed);      // quad_perm xor2
      packed = dppumin<0x124, 0xf>(packed);     // row_ror:4
      packed = dppumin<0x128, 0xf>(packed);     // row_ror:8 -> row16 min
      { unsigned int o = swz_xor16(packed); packed = packed < o ? packed : o; }
      // all 64 lanes now hold the 32-col min (halves identical by mirroring)
      int j1 = (int)(packed & 31u);             // first-min column (VGPR)
      int pj1 = bperm_i(p_j, j1);               // p[j1] (VGPR, no SGPR trip)
      int i0n = pj1 < 0 ? 0 : pj1;
      float rowv_n = cs[i0n * 32 + cl];         // speculative next-row read
      float mnv = unsort_f(packed & 0xFFFFFFE0u);
      float delta = mnv - u0;
      if (usedr) u_r += delta;                  // u[p[used]] += delta
      if (usedc) v_j -= delta;                  // v[used]    -= delta
      if (pj1 < 0) {                            // free column -> p[j1] = ri, done
        if (cl == j1) p_j = ri;                 // mirrored update
        break;
      }
      usedc = usedc || (cl == j1);
      usedr = usedr || (cl == pj1);
      i0 = i0n;
      rowv = rowv_n;
      u0 = bperm_f(u_r, i0n);                   // post-update u[i0]
    }
  }

  // column j matched to row p[j] -> contributes cost[p[j]][j] (lanes 0..31 only)
  int pj = p_j < 0 ? 0 : p_j;
  float a = (lane < n) ? cs[pj * 32 + cl] : 0.f;
#pragma unroll
  for (int off = 32; off; off >>= 1) {
    a += __shfl_xor(a, off);
    clfpart += __shfl_xor(clfpart, off);
  }
  if (lane == 0) {
    part[b * 3 + 0] = a;
    part[b * 3 + 1] = clfpart;
    part[b * 3 + 2] = (float)n;
  }

  // ---- fused finalize: last arrival reduces (R9-proven ticket pattern) ----
  __threadfence();                       // release part[b]
  unsigned int t = 0;
  if (lane == 0) t = atomicAdd(counter, 1u);
  t = (unsigned int)__shfl((int)t, 0);
  if (t == NB - 1u) {
    __threadfence();                     // acquire all blocks' part writes
    volatile const float* vp = part;
    double csum = 0.0, lsum = 0.0, nsum = 0.0;
    for (int i = lane; i < NB; i += 64) {
      csum += (double)vp[i * 3 + 0];
      lsum += (double)vp[i * 3 + 1];
      nsum += (double)vp[i * 3 + 2];
    }
#pragma unroll
    for (int off = 32; off; off >>= 1) {
      csum += __shfl_xor(csum, off);
      lsum += __shfl_xor(lsum, off);
      nsum += __shfl_xor(nsum, off);
    }
    if (lane == 0) {
      out[0] = (float)(csum / (nsum * 256.0));  // / sum(point_masks) = 256*sum(n)
      out[1] = (float)(lsum / nsum);            // / sum(line_masks)
    }
  }
}

extern "C" void kernel_launch(void* const* d_in, const int* in_sizes, int n_in,
                              void* d_out, int out_size, void* d_ws, size_t ws_size,
                              hipStream_t stream) {
  const float* pred = (const float*)d_in[0];   // [512,32,256,2] f32
  const float* prob = (const float*)d_in[1];   // [512,32,2] f32
  const float* tgt  = (const float*)d_in[2];   // [512,32,256,2] f32
  const float* lm   = (const float*)d_in[3];   // [512,32] f32
  const int*   clf  = (const int*)d_in[4];     // [512,32] i32

  float* cost_part = (float*)d_ws;                       // 2048*1024 f32 = 8 MB
  float* part = cost_part + (size_t)2048 * 1024;         // 512*3 f32
  unsigned int* counter = (unsigned int*)(part + NB * 3);

  hipMemsetAsync(counter, 0, sizeof(unsigned int), stream);  // stream-ordered, capturable
  cost_kernel<<<NB * 4, 256, 0, stream>>>(pred, tgt, cost_part);
  hung_kernel<<<NB, 64, 0, stream>>>(cost_part, prob, lm, clf, part, counter,
                                     (float*)d_out);
}

// Round 19
// 65.341 us; speedup vs baseline: 1.1177x; 1.0735x over previous
//
#include <hip/hip_runtime.h>
#include <cstdint>
#include <cstddef>

#define NB 512
#define NL 32
#define KD 512     // P*D
#define KSLAB 128  // k-range per cost block (quarter-K)
#define PASS 128   // k per staging pass

// swizzled float-offset of chunk ch (4 floats) of row `row` in a [32][128] pass buffer.
__device__ __forceinline__ int swz128(int row, int ch) {
  int csw = (ch & ~15) | ((ch ^ (row >> 1)) & 15);
  return row * PASS + csw * 4;
}

// ---------------- cost kernel: 2048 blocks x 256 thr (R15-proven; + counter zero) ----------------
__global__ __launch_bounds__(256, 2)
void cost_kernel(const float* __restrict__ pred, const float* __restrict__ tgt,
                 float* __restrict__ cost_part, unsigned int* __restrict__ counter) {
  __shared__ float smem[8192];   // 32 KB: predH[0..4096), tgtH[4096..8192); partials alias
  const int bid = blockIdx.x;
  if (bid == 0 && threadIdx.x == 0) *counter = 0;   // ordered before hung_kernel by stream
  const int b  = bid >> 2;
  const int ks = (bid & 3) * KSLAB;
  const int tid = threadIdx.x;
  float* predH = smem;
  float* tgtH  = smem + 4096;

  const int w = tid >> 6, l = tid & 63;
  const int ti = l >> 3, tj = l & 7;
  float acc[4][4];
#pragma unroll
  for (int a = 0; a < 4; ++a)
#pragma unroll
    for (int c2 = 0; c2 < 4; ++c2) acc[a][c2] = 0.f;

  const size_t base = (size_t)b * (NL * KD) + ks;
#pragma unroll
  for (int it = 0; it < 4; ++it) {
    int chunk = tid + it * 256;
    int row = chunk >> 5, ch = chunk & 31;
    const float4 pv = *reinterpret_cast<const float4*>(pred + base + (size_t)row * KD + ch * 4);
    const float4 tv = *reinterpret_cast<const float4*>(tgt  + base + (size_t)row * KD + ch * 4);
    int off = swz128(row, ch);
    *reinterpret_cast<float4*>(predH + off) = pv;
    *reinterpret_cast<float4*>(tgtH  + off) = tv;
  }
  __syncthreads();
#pragma unroll
  for (int c0 = 0; c0 < 8; ++c0) {
    const int c = (w << 3) + c0;
    float4 pr[4], tg[4];
#pragma unroll
    for (int r = 0; r < 4; ++r) {
      pr[r] = *reinterpret_cast<const float4*>(predH + swz128(4 * ti + r, c));
      tg[r] = *reinterpret_cast<const float4*>(tgtH  + swz128(4 * tj + r, c));
    }
#pragma unroll
    for (int a = 0; a < 4; ++a)
#pragma unroll
      for (int c2 = 0; c2 < 4; ++c2) {
        float d;
        d = pr[a].x - tg[c2].x; acc[a][c2] += d * d;
        d = pr[a].y - tg[c2].y; acc[a][c2] += d * d;
        d = pr[a].z - tg[c2].z; acc[a][c2] += d * d;
        d = pr[a].w - tg[c2].w; acc[a][c2] += d * d;
      }
  }
  __syncthreads();
#pragma unroll
  for (int a = 0; a < 4; ++a)
#pragma unroll
    for (int c2 = 0; c2 < 4; ++c2)
      smem[w * 1024 + (ti & 3) + 4 * tj + 32 * a + 128 * c2 + 512 * (ti >> 2)] = acc[a][c2];
  __syncthreads();
  const int ti2 = tid >> 5, a2 = (tid >> 3) & 3, tj2 = tid & 7;
  float ov[4];
#pragma unroll
  for (int k = 0; k < 4; ++k) {
    int ad = (ti2 & 3) + 4 * tj2 + 32 * a2 + 128 * k + 512 * (ti2 >> 2);
    ov[k] = (smem[ad] + smem[ad + 1024]) + (smem[ad + 2048] + smem[ad + 3072]);
  }
  *reinterpret_cast<float4*>(cost_part + (size_t)bid * 1024 + tid * 4) =
      make_float4(ov[0], ov[1], ov[2], ov[3]);
}

// ---------------- hungarian + fused finalize: 512 blocks x 64 thr ----------------
__device__ __forceinline__ float readlane_f(float x, int lane) {
  return __int_as_float(__builtin_amdgcn_readlane(__float_as_int(x), lane));
}

template<int CTRL, int RM>
__device__ __forceinline__ unsigned int dppumin(unsigned int x) {
  unsigned int m = (unsigned int)__builtin_amdgcn_update_dpp((int)x, (int)x, CTRL, RM, 0xf, false);
  return x < m ? x : m;   // v_min_u32
}
// u32 min over lanes 0..31 -> wave-uniform scalar (R15-proven reduce shape)
__device__ __forceinline__ unsigned int wave_umin32_bcast(unsigned int x) {
  x = dppumin<0xB1, 0xf>(x);   // quad_perm xor1
  x = dppumin<0x4E, 0xf>(x);   // quad_perm xor2
  x = dppumin<0x124, 0xf>(x);  // row_ror:4
  x = dppumin<0x128, 0xf>(x);  // row_ror:8 -> row16 min everywhere
  x = dppumin<0x142, 0xa>(x);  // row_bcast:15 -> lanes 16..31 = min(lanes 0..31)
  return (unsigned int)__builtin_amdgcn_readlane((int)x, 31);
}
// inverse of the monotone f32->u32 sortable map (scalar ops on uniform value)
__device__ __forceinline__ float unsort_f(unsigned int y) {
  unsigned int x = (y & 0x80000000u) ? (y ^ 0x80000000u) : ~y;
  return __uint_as_float(x);
}

__global__ __launch_bounds__(64)
void hung_kernel(const float* __restrict__ cost_part,
                 const float* __restrict__ prob,
                 const float* __restrict__ lmask,
                 const int* __restrict__ clf,
                 float* __restrict__ part,
                 unsigned int* __restrict__ counter,   // zeroed by cost_kernel
                 float* __restrict__ out) {
  __shared__ float cs[1024];    // cost[32][32]: row read = conflict-free ds_read_b32
  const int b = blockIdx.x;
  const int lane = threadIdx.x;
  const int cl = lane & 31;

  // stage cost = sum of the batch's four K-slab partial planes
  {
    const float4* p0 = reinterpret_cast<const float4*>(cost_part + (size_t)(4 * b + 0) * 1024);
    const float4* p1 = reinterpret_cast<const float4*>(cost_part + (size_t)(4 * b + 1) * 1024);
    const float4* p2 = reinterpret_cast<const float4*>(cost_part + (size_t)(4 * b + 2) * 1024);
    const float4* p3 = reinterpret_cast<const float4*>(cost_part + (size_t)(4 * b + 3) * 1024);
    float4* cs4 = reinterpret_cast<float4*>(cs);
#pragma unroll
    for (int k = 0; k < 4; ++k) {
      int i = lane + 64 * k;
      float4 x0 = p0[i], x1 = p1[i], x2 = p2[i], x3 = p3[i];
      cs4[i] = make_float4((x0.x + x1.x) + (x2.x + x3.x),
                           (x0.y + x1.y) + (x2.y + x3.y),
                           (x0.z + x1.z) + (x2.z + x3.z),
                           (x0.w + x1.w) + (x2.w + x3.w));
    }
  }

  float lm = (lane < 32) ? lmask[b * 32 + lane] : 0.f;
  const int n = __popcll(__ballot(lm > 0.5f));
  float clfpart = 0.f;
  if (lane < 32 && lm > 0.5f) {
    int cc = clf[b * 32 + lane];
    clfpart = -logf(prob[(size_t)(b * 32 + lane) * 2 + cc]);
  }
  __syncthreads();   // cs visible

  const float FINF = 1e30f;
  const bool activecol = (lane < n);

  // Reference-faithful broken JV (minv/way never persisted in the python).
  // R15-proven packed-argmin chain, with WAVE-UNIFORM p[]/freemask in SGPRs:
  //  - free32: bit j set <=> column j free (scalar bit test, no readlane)
  //  - pp0..pp7: p[] packed byte-per-column (7 s_cselect extract, no readlane)
  //  - exact-min readlane dropped: mnv = unsort(pmin & ~31) (<=31 ulp in delta;
  //    same quantization class as R15/R17 which measured absmax 0.0)
  float u_r = 0.f, v_j = 0.f;
  unsigned int free32 = (n >= 32) ? 0xFFFFFFFFu : ((1u << n) - 1u);
  unsigned int pp0 = 0, pp1 = 0, pp2 = 0, pp3 = 0, pp4 = 0, pp5 = 0, pp6 = 0, pp7 = 0;

  for (int ri = 0; ri < n; ++ri) {
    int i0 = ri;
    bool usedc = false;
    bool usedr = (lane == ri);
    float rowv = cs[i0 * 32 + cl];
    float u0 = readlane_f(u_r, i0);
    while (true) {
      float key = rowv - v_j;                   // reduced cost (sans uniform u0)
      float m = (activecol && !usedc) ? key : FINF;
      unsigned int mu = __float_as_uint(m);
      mu ^= (unsigned int)((int)mu >> 31) | 0x80000000u;   // monotone f32->u32
      unsigned int packed = (mu & 0xFFFFFFE0u) | (unsigned int)cl;
      unsigned int pmin = wave_umin32_bcast(packed);       // SGPR
      int j1 = (int)(pmin & 31u);               // first-min column (scalar)
      // p[j1] extract: 7 scalar cselects + shift (replaces readlane)
      unsigned int t0 = (j1 & 16) ? pp4 : pp0;
      unsigned int t1 = (j1 & 16) ? pp5 : pp1;
      unsigned int t2 = (j1 & 16) ? pp6 : pp2;
      unsigned int t3 = (j1 & 16) ? pp7 : pp3;
      unsigned int s0 = (j1 & 8) ? t2 : t0;
      unsigned int s1 = (j1 & 8) ? t3 : t1;
      unsigned int r0 = (j1 & 4) ? s1 : s0;
      int pbyte = (int)((r0 >> ((j1 & 3) * 8)) & 0xFFu);
      bool isfree = (free32 >> j1) & 1u;        // scalar bit test
      int i0n = pbyte & 31;                     // valid when occupied; safe clamp else
      float rowv_n = cs[i0n * 32 + cl];         // speculative next-row read
      float mnv = unsort_f(pmin & 0xFFFFFFE0u); // exact to <=31 ulp
      float delta = mnv - u0;
      if (usedr) u_r += delta;                  // u[p[used]] += delta
      if (usedc) v_j -= delta;                  // v[used]    -= delta
      if (isfree) {                             // p[j1] = ri; done
        unsigned int sh = (unsigned int)(j1 & 3) * 8u;
        unsigned int msk = 0xFFu << sh;
        unsigned int ins = ((unsigned int)ri) << sh;
        int rsel = j1 >> 2;
        pp0 = (rsel == 0) ? ((pp0 & ~msk) | ins) : pp0;
        pp1 = (rsel == 1) ? ((pp1 & ~msk) | ins) : pp1;
        pp2 = (rsel == 2) ? ((pp2 & ~msk) | ins) : pp2;
        pp3 = (rsel == 3) ? ((pp3 & ~msk) | ins) : pp3;
        pp4 = (rsel == 4) ? ((pp4 & ~msk) | ins) : pp4;
        pp5 = (rsel == 5) ? ((pp5 & ~msk) | ins) : pp5;
        pp6 = (rsel == 6) ? ((pp6 & ~msk) | ins) : pp6;
        pp7 = (rsel == 7) ? ((pp7 & ~msk) | ins) : pp7;
        free32 &= ~(1u << j1);
        break;
      }
      usedc = usedc || (lane == j1);
      usedr = usedr || (lane == i0n);
      i0 = i0n;
      rowv = rowv_n;
      u0 = readlane_f(u_r, i0);                 // post-update u[i0] (off crit path)
    }
  }

  // column j matched to row p[j] -> contributes cost[p[j]][j]
  // per-lane extract of p[lane] from the uniform pack (once, outside the loop)
  unsigned int g0 = (lane & 16) ? pp4 : pp0;
  unsigned int g1 = (lane & 16) ? pp5 : pp1;
  unsigned int g2 = (lane & 16) ? pp6 : pp2;
  unsigned int g3 = (lane & 16) ? pp7 : pp3;
  unsigned int h0 = (lane & 8) ? g2 : g0;
  unsigned int h1 = (lane & 8) ? g3 : g1;
  unsigned int gr = (lane & 4) ? h1 : h0;
  int pj = (int)((gr >> ((lane & 3) * 8)) & 0xFFu) & 31;
  float a = activecol ? cs[pj * 32 + cl] : 0.f;
#pragma unroll
  for (int off = 32; off; off >>= 1) {
    a += __shfl_xor(a, off);
    clfpart += __shfl_xor(clfpart, off);
  }
  if (lane == 0) {
    part[b * 3 + 0] = a;
    part[b * 3 + 1] = clfpart;
    part[b * 3 + 2] = (float)n;
  }

  // ---- fused finalize: last arrival reduces (R9-proven ticket pattern) ----
  __threadfence();                       // release part[b]
  unsigned int t = 0;
  if (lane == 0) t = atomicAdd(counter, 1u);
  t = (unsigned int)__shfl((int)t, 0);
  if (t == NB - 1u) {
    __threadfence();                     // acquire all blocks' part writes
    volatile const float* vp = part;
    double csum = 0.0, lsum = 0.0, nsum = 0.0;
    for (int i = lane; i < NB; i += 64) {
      csum += (double)vp[i * 3 + 0];
      lsum += (double)vp[i * 3 + 1];
      nsum += (double)vp[i * 3 + 2];
    }
#pragma unroll
    for (int off = 32; off; off >>= 1) {
      csum += __shfl_xor(csum, off);
      lsum += __shfl_xor(lsum, off);
      nsum += __shfl_xor(nsum, off);
    }
    if (lane == 0) {
      out[0] = (float)(csum / (nsum * 256.0));  // / sum(point_masks) = 256*sum(n)
      out[1] = (float)(lsum / nsum);            // / sum(line_masks)
    }
  }
}

extern "C" void kernel_launch(void* const* d_in, const int* in_sizes, int n_in,
                              void* d_out, int out_size, void* d_ws, size_t ws_size,
                              hipStream_t stream) {
  const float* pred = (const float*)d_in[0];   // [512,32,256,2] f32
  const float* prob = (const float*)d_in[1];   // [512,32,2] f32
  const float* tgt  = (const float*)d_in[2];   // [512,32,256,2] f32
  const float* lm   = (const float*)d_in[3];   // [512,32] f32
  const int*   clf  = (const int*)d_in[4];     // [512,32] i32

  float* cost_part = (float*)d_ws;                       // 2048*1024 f32 = 8 MB
  float* part = cost_part + (size_t)2048 * 1024;         // 512*3 f32
  unsigned int* counter = (unsigned int*)(part + NB * 3);

  cost_kernel<<<NB * 4, 256, 0, stream>>>(pred, tgt, cost_part, counter);
  hung_kernel<<<NB, 64, 0, stream>>>(cost_part, prob, lm, clf, part, counter,
                                     (float*)d_out);
}

// Round 20
// 59.661 us; speedup vs baseline: 1.2241x; 1.0952x over previous
//
#include <hip/hip_runtime.h>
#include <cstdint>
#include <cstddef>

#define NB 512
#define NL 32
#define KD 512     // P*D
#define KSLAB 128  // k-range per cost block (quarter-K)
#define PASS 128   // k per staging pass

// swizzled float-offset of chunk ch (4 floats) of row `row` in a [32][128] pass buffer.
__device__ __forceinline__ int swz128(int row, int ch) {
  int csw = (ch & ~15) | ((ch ^ (row >> 1)) & 15);
  return row * PASS + csw * 4;
}

// ---------------- cost kernel: 2048 blocks x 256 thr (R15-proven; + counter zero) ----------------
__global__ __launch_bounds__(256, 2)
void cost_kernel(const float* __restrict__ pred, const float* __restrict__ tgt,
                 float* __restrict__ cost_part, unsigned int* __restrict__ counter) {
  __shared__ float smem[8192];   // 32 KB: predH[0..4096), tgtH[4096..8192); partials alias
  const int bid = blockIdx.x;
  if (bid == 0 && threadIdx.x == 0) *counter = 0;   // ordered before hung_kernel by stream
  const int b  = bid >> 2;
  const int ks = (bid & 3) * KSLAB;
  const int tid = threadIdx.x;
  float* predH = smem;
  float* tgtH  = smem + 4096;

  const int w = tid >> 6, l = tid & 63;
  const int ti = l >> 3, tj = l & 7;
  float acc[4][4];
#pragma unroll
  for (int a = 0; a < 4; ++a)
#pragma unroll
    for (int c2 = 0; c2 < 4; ++c2) acc[a][c2] = 0.f;

  const size_t base = (size_t)b * (NL * KD) + ks;
#pragma unroll
  for (int it = 0; it < 4; ++it) {
    int chunk = tid + it * 256;
    int row = chunk >> 5, ch = chunk & 31;
    const float4 pv = *reinterpret_cast<const float4*>(pred + base + (size_t)row * KD + ch * 4);
    const float4 tv = *reinterpret_cast<const float4*>(tgt  + base + (size_t)row * KD + ch * 4);
    int off = swz128(row, ch);
    *reinterpret_cast<float4*>(predH + off) = pv;
    *reinterpret_cast<float4*>(tgtH  + off) = tv;
  }
  __syncthreads();
#pragma unroll
  for (int c0 = 0; c0 < 8; ++c0) {
    const int c = (w << 3) + c0;
    float4 pr[4], tg[4];
#pragma unroll
    for (int r = 0; r < 4; ++r) {
      pr[r] = *reinterpret_cast<const float4*>(predH + swz128(4 * ti + r, c));
      tg[r] = *reinterpret_cast<const float4*>(tgtH  + swz128(4 * tj + r, c));
    }
#pragma unroll
    for (int a = 0; a < 4; ++a)
#pragma unroll
      for (int c2 = 0; c2 < 4; ++c2) {
        float d;
        d = pr[a].x - tg[c2].x; acc[a][c2] += d * d;
        d = pr[a].y - tg[c2].y; acc[a][c2] += d * d;
        d = pr[a].z - tg[c2].z; acc[a][c2] += d * d;
        d = pr[a].w - tg[c2].w; acc[a][c2] += d * d;
      }
  }
  __syncthreads();
#pragma unroll
  for (int a = 0; a < 4; ++a)
#pragma unroll
    for (int c2 = 0; c2 < 4; ++c2)
      smem[w * 1024 + (ti & 3) + 4 * tj + 32 * a + 128 * c2 + 512 * (ti >> 2)] = acc[a][c2];
  __syncthreads();
  const int ti2 = tid >> 5, a2 = (tid >> 3) & 3, tj2 = tid & 7;
  float ov[4];
#pragma unroll
  for (int k = 0; k < 4; ++k) {
    int ad = (ti2 & 3) + 4 * tj2 + 32 * a2 + 128 * k + 512 * (ti2 >> 2);
    ov[k] = (smem[ad] + smem[ad + 1024]) + (smem[ad + 2048] + smem[ad + 3072]);
  }
  *reinterpret_cast<float4*>(cost_part + (size_t)bid * 1024 + tid * 4) =
      make_float4(ov[0], ov[1], ov[2], ov[3]);
}

// ---------------- hungarian + fused finalize: 512 blocks x 64 thr ----------------
// Walk body = R15-EXACT (best measured: 39.1 us vs 43.1 bpermute / 44.3 SGPR-pack).
__device__ __forceinline__ float readlane_f(float x, int lane) {
  return __int_as_float(__builtin_amdgcn_readlane(__float_as_int(x), lane));
}
__device__ __forceinline__ int readlane_i(int x, int lane) {
  return __builtin_amdgcn_readlane(x, lane);
}

template<int CTRL, int RM>
__device__ __forceinline__ unsigned int dppumin(unsigned int x) {
  unsigned int m = (unsigned int)__builtin_amdgcn_update_dpp((int)x, (int)x, CTRL, RM, 0xf, false);
  return x < m ? x : m;   // v_min_u32
}
// u32 min over lanes 0..31, returned as wave-uniform scalar
__device__ __forceinline__ unsigned int wave_umin32_bcast(unsigned int x) {
  x = dppumin<0xB1, 0xf>(x);   // quad_perm xor1
  x = dppumin<0x4E, 0xf>(x);   // quad_perm xor2
  x = dppumin<0x124, 0xf>(x);  // row_ror:4
  x = dppumin<0x128, 0xf>(x);  // row_ror:8 -> row16 min everywhere
  x = dppumin<0x142, 0xa>(x);  // row_bcast:15 -> lanes 16..31 = min(lanes 0..31)
  return (unsigned int)__builtin_amdgcn_readlane((int)x, 31);
}

__global__ __launch_bounds__(64)
void hung_kernel(const float* __restrict__ cost_part,
                 const float* __restrict__ prob,
                 const float* __restrict__ lmask,
                 const int* __restrict__ clf,
                 float* __restrict__ part,
                 unsigned int* __restrict__ counter,   // zeroed by cost_kernel
                 float* __restrict__ out) {
  __shared__ float cs[1024];    // cost[32][32]: row-select = 1 conflict-free ds_read_b32
  const int b = blockIdx.x;
  const int lane = threadIdx.x;

  // stage cost = sum of the batch's four K-slab partial planes
  {
    const float4* p0 = reinterpret_cast<const float4*>(cost_part + (size_t)(4 * b + 0) * 1024);
    const float4* p1 = reinterpret_cast<const float4*>(cost_part + (size_t)(4 * b + 1) * 1024);
    const float4* p2 = reinterpret_cast<const float4*>(cost_part + (size_t)(4 * b + 2) * 1024);
    const float4* p3 = reinterpret_cast<const float4*>(cost_part + (size_t)(4 * b + 3) * 1024);
    float4* cs4 = reinterpret_cast<float4*>(cs);
#pragma unroll
    for (int k = 0; k < 4; ++k) {
      int i = lane + 64 * k;
      float4 x0 = p0[i], x1 = p1[i], x2 = p2[i], x3 = p3[i];
      cs4[i] = make_float4((x0.x + x1.x) + (x2.x + x3.x),
                           (x0.y + x1.y) + (x2.y + x3.y),
                           (x0.z + x1.z) + (x2.z + x3.z),
                           (x0.w + x1.w) + (x2.w + x3.w));
    }
  }

  float lm = (lane < 32) ? lmask[b * 32 + lane] : 0.f;
  const int n = __popcll(__ballot(lm > 0.5f));
  float clfpart = 0.f;
  if (lane < 32 && lm > 0.5f) {
    int cc = clf[b * 32 + lane];
    clfpart = -logf(prob[(size_t)(b * 32 + lane) * 2 + cc]);
  }
  __syncthreads();   // cs visible

  const float FINF = 1e30f;
  const bool activecol = (lane < n);
  const int cl = lane & 31;   // lanes 32..63 mirror -> same-addr broadcast (free)

  // Reference-faithful broken JV (minv/way never persisted in the python):
  // each step: fresh argmin over free cols of cost[i0][j]-u[i0]-v[j];
  // "augment" collapses to p[j_final] = ri. Packed sortable-u32 argmin
  // (R15-proven): 5 LSBs hold lane idx -> one v_min_u32 DPP cascade gives
  // min AND first-index argmin in one scalar.
  float u_r = 0.f, v_j = 0.f;
  int p_j = -1;

  for (int ri = 0; ri < n; ++ri) {
    int i0 = ri;
    bool usedc = false;
    bool usedr = (lane == ri);
    float rowv = cs[i0 * 32 + cl];
    float u0 = readlane_f(u_r, i0);
    while (true) {
      float key = rowv - v_j;                   // reduced cost (sans uniform u0)
      bool act = activecol && !usedc;
      float m = act ? key : FINF;
      unsigned int mu = __float_as_uint(m);
      mu ^= (unsigned int)((int)mu >> 31) | 0x80000000u;   // monotone f32->u32
      unsigned int packed = (mu & 0xFFFFFFE0u) | (unsigned int)cl;
      unsigned int pmin = wave_umin32_bcast(packed);
      int j1 = (int)(pmin & 31u);               // first-min column
      float mnv = readlane_f(m, j1);            // exact min value
      int pj1 = readlane_i(p_j, j1);
      float delta = mnv - u0;
      if (usedr) u_r += delta;                  // u[p[used]] += delta
      if (usedc) v_j -= delta;                  // v[used]    -= delta
      if (pj1 < 0) {                            // free column -> p[j1] = ri, done
        if (lane == j1) p_j = ri;
        break;
      }
      usedc = usedc || (lane == j1);
      usedr = usedr || (lane == pj1);
      i0 = pj1;
      rowv = cs[i0 * 32 + cl];
      u0 = readlane_f(u_r, i0);                 // post-update u[i0]
    }
  }

  // column j matched to row p[j] -> contributes cost[p[j]][j]
  int pj = p_j < 0 ? 0 : p_j;
  float a = activecol ? cs[pj * 32 + cl] : 0.f;
#pragma unroll
  for (int off = 32; off; off >>= 1) {
    a += __shfl_xor(a, off);
    clfpart += __shfl_xor(clfpart, off);
  }
  if (lane == 0) {
    part[b * 3 + 0] = a;
    part[b * 3 + 1] = clfpart;
    part[b * 3 + 2] = (float)n;
  }

  // ---- fused finalize: last arrival reduces (R9-proven ticket pattern) ----
  __threadfence();                       // release part[b]
  unsigned int t = 0;
  if (lane == 0) t = atomicAdd(counter, 1u);
  t = (unsigned int)__shfl((int)t, 0);
  if (t == NB - 1u) {
    __threadfence();                     // acquire all blocks' part writes
    volatile const float* vp = part;
    double csum = 0.0, lsum = 0.0, nsum = 0.0;
    for (int i = lane; i < NB; i += 64) {
      csum += (double)vp[i * 3 + 0];
      lsum += (double)vp[i * 3 + 1];
      nsum += (double)vp[i * 3 + 2];
    }
#pragma unroll
    for (int off = 32; off; off >>= 1) {
      csum += __shfl_xor(csum, off);
      lsum += __shfl_xor(lsum, off);
      nsum += __shfl_xor(nsum, off);
    }
    if (lane == 0) {
      out[0] = (float)(csum / (nsum * 256.0));  // / sum(point_masks) = 256*sum(n)
      out[1] = (float)(lsum / nsum);            // / sum(line_masks)
    }
  }
}

extern "C" void kernel_launch(void* const* d_in, const int* in_sizes, int n_in,
                              void* d_out, int out_size, void* d_ws, size_t ws_size,
                              hipStream_t stream) {
  const float* pred = (const float*)d_in[0];   // [512,32,256,2] f32
  const float* prob = (const float*)d_in[1];   // [512,32,2] f32
  const float* tgt  = (const float*)d_in[2];   // [512,32,256,2] f32
  const float* lm   = (const float*)d_in[3];   // [512,32] f32
  const int*   clf  = (const int*)d_in[4];     // [512,32] i32

  float* cost_part = (float*)d_ws;                       // 2048*1024 f32 = 8 MB
  float* part = cost_part + (size_t)2048 * 1024;         // 512*3 f32
  unsigned int* counter = (unsigned int*)(part + NB * 3);

  cost_kernel<<<NB * 4, 256, 0, stream>>>(pred, tgt, cost_part, counter);
  hung_kernel<<<NB, 64, 0, stream>>>(cost_part, prob, lm, clf, part, counter,
                                     (float*)d_out);
}